// Round 5
// baseline (240.621 us; speedup 1.0000x reference)
//
#include <hip/hip_runtime.h>

#define NB 8
#define NT 1024
#define ND 1024
#define NH 16
#define NDH 64
#define NM (NB*NT)   // 8192 rows
#define LNEPS 1e-5f

typedef __attribute__((ext_vector_type(8))) __bf16 bf16x8;
typedef __attribute__((ext_vector_type(4))) float f32x4;

// ---------------- W (K x N f32) -> WT (N x K bf16), both W1 and W2 ----------------
__global__ void transpose_to_bf16(const float* __restrict__ W1, const float* __restrict__ W2,
                                  __bf16* __restrict__ WT1, __bf16* __restrict__ WT2) {
    __shared__ float tile[32][33];
    const float* W = blockIdx.z ? W2 : W1;
    __bf16* WT = blockIdx.z ? WT2 : WT1;
    int bx = blockIdx.x * 32;  // n base
    int by = blockIdx.y * 32;  // k base
    int tx = threadIdx.x;      // 0..31
    int ty = threadIdx.y;      // 0..7
    for (int i = ty; i < 32; i += 8)
        tile[i][tx] = W[(size_t)(by + i) * ND + bx + tx];
    __syncthreads();
    for (int i = ty; i < 32; i += 8)
        WT[(size_t)(bx + i) * ND + by + tx] = (__bf16)tile[tx][i];
}

// ---------------- xsum[b,c] += partial sums over t ----------------
__global__ void xsum_kernel(const float* __restrict__ x, float* __restrict__ xsum) {
    int b = blockIdx.x;
    int chunk = blockIdx.y;
    int tid = threadIdx.x;
    const float4* xp = (const float4*)(x + ((size_t)b * NT + chunk * 16) * ND) + tid;
    float4 s = {0.f, 0.f, 0.f, 0.f};
    #pragma unroll
    for (int t = 0; t < 16; ++t) {
        float4 v = xp[(size_t)t * (ND / 4)];
        s.x += v.x; s.y += v.y; s.z += v.z; s.w += v.w;
    }
    float* dst = xsum + b * ND + tid * 4;
    atomicAdd(dst + 0, s.x);
    atomicAdd(dst + 1, s.y);
    atomicAdd(dst + 2, s.z);
    atomicAdd(dst + 3, s.w);
}

// ------- per (b,h): ksum,vsum = xsum@Wk/Wv ; wqk = (Wq@ksum)/8 -------
__global__ void head_prep(const float* __restrict__ xsum,
                          const float* __restrict__ Wq, const float* __restrict__ Wk,
                          const float* __restrict__ Wv,
                          float* __restrict__ vsum, float* __restrict__ wqk) {
    int h = blockIdx.x, b = blockIdx.y;
    int t = threadIdx.x;
    int d = t & 63, q = t >> 6;  // quarter 0..3
    __shared__ float part[2][4][NDH];
    __shared__ float ks[NDH];
    const float* xs = xsum + b * ND;
    float sk = 0.f, sv = 0.f;
    #pragma unroll 4
    for (int c = q * 256; c < q * 256 + 256; ++c) {
        float xv = xs[c];
        sk += xv * Wk[((size_t)h * ND + c) * NDH + d];
        sv += xv * Wv[((size_t)h * ND + c) * NDH + d];
    }
    part[0][q][d] = sk;
    part[1][q][d] = sv;
    __syncthreads();
    if (t < 64) {
        ks[t] = part[0][0][t] + part[0][1][t] + part[0][2][t] + part[0][3][t];
    } else if (t < 128) {
        int dd = t - 64;
        vsum[((size_t)b * NH + h) * NDH + dd] =
            part[1][0][dd] + part[1][1][dd] + part[1][2][dd] + part[1][3][dd];
    }
    __syncthreads();
    for (int c = t; c < ND; c += 256) {
        const float* wq = Wq + ((size_t)h * ND + c) * NDH;
        float s = 0.f;
        #pragma unroll 16
        for (int dd = 0; dd < NDH; ++dd) s += wq[dd] * ks[dd];
        wqk[((size_t)b * NH + h) * ND + c] = s * 0.125f;
    }
}

// ---------------- rowsum[b,h,t] = x[b,t,:] . wqk[b,h,:] ----------------
__global__ __launch_bounds__(256) void rowsum_kernel(const float* __restrict__ x,
                                                     const float* __restrict__ wqk,
                                                     float* __restrict__ rowsum) {
    int tc = blockIdx.x, b = blockIdx.y;
    int tid = threadIdx.x, wid = tid >> 6, lane = tid & 63;
    int t0 = tc * 16 + wid * 4;
    float acc[4][16];
    #pragma unroll
    for (int tq = 0; tq < 4; ++tq)
        #pragma unroll
        for (int h = 0; h < 16; ++h) acc[tq][h] = 0.f;
    const float4* wb = (const float4*)(wqk + (size_t)b * NH * ND);
    #pragma unroll
    for (int chunk = 0; chunk < 4; ++chunk) {
        float4 xv[4];
        #pragma unroll
        for (int tq = 0; tq < 4; ++tq)
            xv[tq] = ((const float4*)(x + ((size_t)b * NT + t0 + tq) * ND))[chunk * 64 + lane];
        #pragma unroll
        for (int h = 0; h < 16; ++h) {
            float4 wv = wb[h * 256 + chunk * 64 + lane];
            #pragma unroll
            for (int tq = 0; tq < 4; ++tq)
                acc[tq][h] += xv[tq].x * wv.x + xv[tq].y * wv.y +
                              xv[tq].z * wv.z + xv[tq].w * wv.w;
        }
    }
    bool c0 = lane & 1, c1 = lane & 2, c2 = lane & 4, c3 = lane & 8;
    float out4[4];
    #pragma unroll
    for (int tq = 0; tq < 4; ++tq) {
        float w8[8];
        #pragma unroll
        for (int j = 0; j < 8; ++j) {
            float send = c0 ? acc[tq][2 * j] : acc[tq][2 * j + 1];
            float recv = __shfl_xor(send, 1, 64);
            w8[j] = (c0 ? acc[tq][2 * j + 1] : acc[tq][2 * j]) + recv;
        }
        float u4[4];
        #pragma unroll
        for (int j = 0; j < 4; ++j) {
            float send = c1 ? w8[2 * j] : w8[2 * j + 1];
            float recv = __shfl_xor(send, 2, 64);
            u4[j] = (c1 ? w8[2 * j + 1] : w8[2 * j]) + recv;
        }
        float s2[2];
        #pragma unroll
        for (int j = 0; j < 2; ++j) {
            float send = c2 ? u4[2 * j] : u4[2 * j + 1];
            float recv = __shfl_xor(send, 4, 64);
            s2[j] = (c2 ? u4[2 * j + 1] : u4[2 * j]) + recv;
        }
        float send = c3 ? s2[0] : s2[1];
        float recv = __shfl_xor(send, 8, 64);
        float r = (c3 ? s2[1] : s2[0]) + recv;
        r += __shfl_xor(r, 16, 64);
        r += __shfl_xor(r, 32, 64);
        out4[tq] = r;
    }
    if (lane < 16) {
        float4 o = {out4[0], out4[1], out4[2], out4[3]};
        *(float4*)(rowsum + ((size_t)b * NH + lane) * NT + t0) = o;
    }
}

// ---------------- softmax over t, in place ----------------
__global__ void softmax_kernel(float* __restrict__ rs) {
    int bh = blockIdx.x, tid = threadIdx.x;
    int wave = tid >> 6, lane = tid & 63;
    float* row = rs + (size_t)bh * NT;
    float4 v = ((float4*)row)[tid];
    float m = fmaxf(fmaxf(v.x, v.y), fmaxf(v.z, v.w));
    __shared__ float red[4];
    for (int off = 32; off; off >>= 1) m = fmaxf(m, __shfl_down(m, off, 64));
    if (lane == 0) red[wave] = m;
    __syncthreads();
    m = fmaxf(fmaxf(red[0], red[1]), fmaxf(red[2], red[3]));
    __syncthreads();
    float4 e;
    e.x = __expf(v.x - m); e.y = __expf(v.y - m);
    e.z = __expf(v.z - m); e.w = __expf(v.w - m);
    float s = e.x + e.y + e.z + e.w;
    for (int off = 32; off; off >>= 1) s += __shfl_down(s, off, 64);
    if (lane == 0) red[wave] = s;
    __syncthreads();
    s = red[0] + red[1] + red[2] + red[3];
    float inv = 1.f / s;
    e.x *= inv; e.y *= inv; e.z *= inv; e.w *= inv;
    ((float4*)row)[tid] = e;
}

// ---------------- LN1: x1 = LN(x + attn_out) -> bf16 ----------------
__global__ void ln1_kernel(const float* __restrict__ x, const float* __restrict__ p,
                           const float* __restrict__ vsum,
                           const float* __restrict__ g1, const float* __restrict__ b1,
                           __bf16* __restrict__ x1b) {
    int t = blockIdx.x, b = blockIdx.y, tid = threadIdx.x;
    int wave = tid >> 6, lane = tid & 63;
    size_t rowoff = ((size_t)b * NT + t) * ND;
    float4 xv = ((const float4*)(x + rowoff))[tid];
    int h = tid >> 4;  // c = tid*4 -> head = c/64
    float pv = p[((size_t)b * NH + h) * NT + t];
    float4 vs = ((const float4*)(vsum + ((size_t)b * NH + h) * NDH))[tid & 15];
    float4 s;
    s.x = xv.x + pv * vs.x; s.y = xv.y + pv * vs.y;
    s.z = xv.z + pv * vs.z; s.w = xv.w + pv * vs.w;
    float sum = s.x + s.y + s.z + s.w;
    float sq = s.x * s.x + s.y * s.y + s.z * s.z + s.w * s.w;
    __shared__ float rs_[4], rq_[4];
    for (int off = 32; off; off >>= 1) {
        sum += __shfl_down(sum, off, 64);
        sq += __shfl_down(sq, off, 64);
    }
    if (lane == 0) { rs_[wave] = sum; rq_[wave] = sq; }
    __syncthreads();
    sum = rs_[0] + rs_[1] + rs_[2] + rs_[3];
    sq = rq_[0] + rq_[1] + rq_[2] + rq_[3];
    float mu = sum * (1.f / ND);
    float var = sq * (1.f / ND) - mu * mu;
    float rstd = rsqrtf(var + LNEPS);
    float4 g = ((const float4*)g1)[tid];
    float4 bb = ((const float4*)b1)[tid];
    union { __bf16 h4[4]; uint2 u; } pk;
    pk.h4[0] = (__bf16)((s.x - mu) * rstd * g.x + bb.x);
    pk.h4[1] = (__bf16)((s.y - mu) * rstd * g.y + bb.y);
    pk.h4[2] = (__bf16)((s.z - mu) * rstd * g.z + bb.z);
    pk.h4[3] = (__bf16)((s.w - mu) * rstd * g.w + bb.w);
    ((uint2*)(x1b + rowoff))[tid] = pk.u;
}

// ---------------- bf16 MFMA GEMM: BK=64, XOR-swizzled LDS, XCD swizzle ----------------
// C = A(8192xK) @ B, BT = B^T (NxK). Writes bf16. RELU=1 applies relu.
// Swizzle (rule #21, both-sides): gload_lds dest is LINEAR; per-lane GLOBAL source
// k-byte is XOR'd with ((row&7)<<4); every ds_read applies the same XOR.
template <int RELU>
__global__ __launch_bounds__(256) void gemm_bf16(const __bf16* __restrict__ A,
                                                 const __bf16* __restrict__ BT,
                                                 __bf16* __restrict__ Cout) {
    const int K = 1024, N = 1024;
    __shared__ __bf16 As[128 * 64];
    __shared__ __bf16 Bs[128 * 64];
    int raw = blockIdx.x;
    int swz = (raw & 7) * 64 + (raw >> 3);   // XCD k owns swz in [k*64, k*64+64)
    int m0 = (swz >> 3) * 128;               // 8 m-panels per XCD
    int n0 = (swz & 7) * 128;                // all 8 n-panels (B L2-resident)
    int tid = threadIdx.x;
    int wid = tid >> 6, lane = tid & 63;
    int wr = wid >> 1, wc = wid & 1;
    int r = lane & 15, g = lane >> 4;
    // staging: call j covers rows j*32..j*32+31; lane l of wave w -> row j*32+w*8+(l>>3),
    // LDS byte (l&7)*16 (linear). Global source byte = ((l&7)*16) ^ (((l>>3)&7)<<4).
    int srow = tid >> 3;                                     // 0..31
    int soff_e = (((tid & 7) * 16) ^ ((srow & 7) << 4)) >> 1; // elements
    const __bf16* Ag = A + (size_t)(m0 + srow) * K + soff_e;
    const __bf16* Bg = BT + (size_t)(n0 + srow) * K + soff_e;
    // fragment read swizzle
    int swz_r = (r & 7) << 4;
    f32x4 acc[4][4] = {};
    for (int k0 = 0; k0 < K; k0 += 64) {
        __syncthreads();  // previous iter's LDS reads done
        #pragma unroll
        for (int j = 0; j < 4; ++j) {
            __builtin_amdgcn_global_load_lds(
                (const __attribute__((address_space(1))) unsigned int*)(Ag + (size_t)(j * 32) * K + k0),
                (__attribute__((address_space(3))) unsigned int*)&As[(j * 32 + wid * 8) * 64], 16, 0, 0);
            __builtin_amdgcn_global_load_lds(
                (const __attribute__((address_space(1))) unsigned int*)(Bg + (size_t)(j * 32) * K + k0),
                (__attribute__((address_space(3))) unsigned int*)&Bs[(j * 32 + wid * 8) * 64], 16, 0, 0);
        }
        __syncthreads();  // compiler drains vmcnt before barrier
        #pragma unroll
        for (int ks = 0; ks < 2; ++ks) {
            int ob = (ks * 64 + g * 16) ^ swz_r;  // byte within 128-B row
            bf16x8 af[4], bf[4];
            #pragma unroll
            for (int mf = 0; mf < 4; ++mf)
                af[mf] = *(const bf16x8*)((const char*)&As[(wr * 64 + mf * 16 + r) * 64] + ob);
            #pragma unroll
            for (int nf = 0; nf < 4; ++nf)
                bf[nf] = *(const bf16x8*)((const char*)&Bs[(wc * 64 + nf * 16 + r) * 64] + ob);
            #pragma unroll
            for (int mf = 0; mf < 4; ++mf)
                #pragma unroll
                for (int nf = 0; nf < 4; ++nf)
                    acc[mf][nf] = __builtin_amdgcn_mfma_f32_16x16x32_bf16(af[mf], bf[nf], acc[mf][nf], 0, 0, 0);
        }
    }
    #pragma unroll
    for (int mf = 0; mf < 4; ++mf) {
        #pragma unroll
        for (int nf = 0; nf < 4; ++nf) {
            int col = n0 + wc * 64 + nf * 16 + r;
            #pragma unroll
            for (int i = 0; i < 4; ++i) {
                int row = m0 + wr * 64 + mf * 16 + g * 4 + i;
                float v = acc[mf][nf][i];
                if (RELU) v = fmaxf(v, 0.f);
                Cout[(size_t)row * N + col] = (__bf16)v;
            }
        }
    }
}

// ---------------- LN2: out = LN(x1 + ff) -> f32 ----------------
__global__ void ln2_kernel(const __bf16* __restrict__ x1b, const __bf16* __restrict__ ffb,
                           float* __restrict__ out,
                           const float* __restrict__ g2, const float* __restrict__ b2) {
    int t = blockIdx.x, b = blockIdx.y, tid = threadIdx.x;
    int wave = tid >> 6, lane = tid & 63;
    size_t rowoff = ((size_t)b * NT + t) * ND;
    union { __bf16 h4[4]; uint2 u; } pk, pf;
    pk.u = ((const uint2*)(x1b + rowoff))[tid];
    pf.u = ((const uint2*)(ffb + rowoff))[tid];
    float4 s;
    s.x = (float)pk.h4[0] + (float)pf.h4[0];
    s.y = (float)pk.h4[1] + (float)pf.h4[1];
    s.z = (float)pk.h4[2] + (float)pf.h4[2];
    s.w = (float)pk.h4[3] + (float)pf.h4[3];
    float sum = s.x + s.y + s.z + s.w;
    float sq = s.x * s.x + s.y * s.y + s.z * s.z + s.w * s.w;
    __shared__ float rs_[4], rq_[4];
    for (int off = 32; off; off >>= 1) {
        sum += __shfl_down(sum, off, 64);
        sq += __shfl_down(sq, off, 64);
    }
    if (lane == 0) { rs_[wave] = sum; rq_[wave] = sq; }
    __syncthreads();
    sum = rs_[0] + rs_[1] + rs_[2] + rs_[3];
    sq = rq_[0] + rq_[1] + rq_[2] + rq_[3];
    float mu = sum * (1.f / ND);
    float var = sq * (1.f / ND) - mu * mu;
    float rstd = rsqrtf(var + LNEPS);
    float4 g = ((const float4*)g2)[tid];
    float4 bb = ((const float4*)b2)[tid];
    float4 o;
    o.x = (s.x - mu) * rstd * g.x + bb.x;
    o.y = (s.y - mu) * rstd * g.y + bb.y;
    o.z = (s.z - mu) * rstd * g.z + bb.z;
    o.w = (s.w - mu) * rstd * g.w + bb.w;
    ((float4*)(out + rowoff))[tid] = o;
}

extern "C" void kernel_launch(void* const* d_in, const int* in_sizes, int n_in,
                              void* d_out, int out_size, void* d_ws, size_t ws_size,
                              hipStream_t stream) {
    const float* x  = (const float*)d_in[0];
    const float* Wq = (const float*)d_in[1];
    const float* Wk = (const float*)d_in[2];
    const float* Wv = (const float*)d_in[3];
    const float* W1 = (const float*)d_in[4];
    const float* W2 = (const float*)d_in[5];
    const float* g1 = (const float*)d_in[6];
    const float* b1 = (const float*)d_in[7];
    const float* g2 = (const float*)d_in[8];
    const float* b2 = (const float*)d_in[9];
    float* out = (float*)d_out;

    char* w = (char*)d_ws;
    float* xsum = (float*)w;   w += (size_t)NB * ND * 4;            // 32 KB
    float* vsum = (float*)w;   w += (size_t)NB * NH * NDH * 4;      // 32 KB
    float* wqk  = (float*)w;   w += (size_t)NB * NH * ND * 4;       // 512 KB
    float* rsum = (float*)w;   w += (size_t)NB * NH * NT * 4;       // 512 KB
    __bf16* x1b = (__bf16*)w;  w += (size_t)NM * ND * 2;            // 16 MB
    __bf16* h1b = (__bf16*)w;  w += (size_t)NM * ND * 2;            // 16 MB
    __bf16* ffb = (__bf16*)w;  w += (size_t)NM * ND * 2;            // 16 MB
    __bf16* w1t = (__bf16*)w;  w += (size_t)ND * ND * 2;            // 2 MB
    __bf16* w2t = (__bf16*)w;  w += (size_t)ND * ND * 2;            // 2 MB

    // zero xsum accumulator (ws is poisoned 0xAA before every launch)
    hipMemsetAsync(xsum, 0, (size_t)NB * ND * 4, stream);

    // weight transpose+convert (f32 KxN -> bf16 NxK), W1 and W2 in one dispatch
    transpose_to_bf16<<<dim3(32, 32, 2), dim3(32, 8), 0, stream>>>(W1, W2, w1t, w2t);

    // attention (algebraically reduced)
    xsum_kernel<<<dim3(NB, 64), 256, 0, stream>>>(x, xsum);
    head_prep<<<dim3(NH, NB), 256, 0, stream>>>(xsum, Wq, Wk, Wv, vsum, wqk);
    rowsum_kernel<<<dim3(64, NB), 256, 0, stream>>>(x, wqk, rsum);
    softmax_kernel<<<NB * NH, 256, 0, stream>>>(rsum);
    ln1_kernel<<<dim3(NT, NB), 256, 0, stream>>>(x, rsum, vsum, g1, b1, x1b);

    // FFN
    gemm_bf16<1><<<512, 256, 0, stream>>>(x1b, w1t, h1b);
    gemm_bf16<0><<<512, 256, 0, stream>>>(h1b, w2t, ffb);
    ln2_kernel<<<dim3(NT, NB), 256, 0, stream>>>(x1b, ffb, out, g2, b2);
}

// Round 7
// 223.847 us; speedup vs baseline: 1.0749x; 1.0749x over previous
//
#include <hip/hip_runtime.h>

#define NB 8
#define NT 1024
#define ND 1024
#define NH 16
#define NDH 64
#define NM (NB*NT)   // 8192 rows
#define LNEPS 1e-5f

typedef __attribute__((ext_vector_type(8))) __bf16 bf16x8;
typedef __attribute__((ext_vector_type(4))) float f32x4;

// ---------------- W (K x N f32) -> WT (N x K bf16), both W1 and W2 ----------------
__global__ void transpose_to_bf16(const float* __restrict__ W1, const float* __restrict__ W2,
                                  __bf16* __restrict__ WT1, __bf16* __restrict__ WT2) {
    __shared__ float tile[32][33];
    const float* W = blockIdx.z ? W2 : W1;
    __bf16* WT = blockIdx.z ? WT2 : WT1;
    int bx = blockIdx.x * 32;  // n base
    int by = blockIdx.y * 32;  // k base
    int tx = threadIdx.x;      // 0..31
    int ty = threadIdx.y;      // 0..7
    for (int i = ty; i < 32; i += 8)
        tile[i][tx] = W[(size_t)(by + i) * ND + bx + tx];
    __syncthreads();
    for (int i = ty; i < 32; i += 8)
        WT[(size_t)(bx + i) * ND + by + tx] = (__bf16)tile[tx][i];
}

// ---------------- xsum[b,c] += partial sums over t ----------------
__global__ void xsum_kernel(const float* __restrict__ x, float* __restrict__ xsum) {
    int b = blockIdx.x;
    int chunk = blockIdx.y;
    int tid = threadIdx.x;
    const float4* xp = (const float4*)(x + ((size_t)b * NT + chunk * 16) * ND) + tid;
    float4 s = {0.f, 0.f, 0.f, 0.f};
    #pragma unroll
    for (int t = 0; t < 16; ++t) {
        float4 v = xp[(size_t)t * (ND / 4)];
        s.x += v.x; s.y += v.y; s.z += v.z; s.w += v.w;
    }
    float* dst = xsum + b * ND + tid * 4;
    atomicAdd(dst + 0, s.x);
    atomicAdd(dst + 1, s.y);
    atomicAdd(dst + 2, s.z);
    atomicAdd(dst + 3, s.w);
}

// ---- ksum[b,h,d], vsum[b,h,d] = sum_c xsum[b,c] * Wk/Wv[h,c,d] ----
// grid (16 h, 16 csplit); coalesced lane=d loads; 8 batches in regs; LDS reduce; atomicAdd.
__global__ __launch_bounds__(256) void ksum_vsum_kernel(const float* __restrict__ xsum,
                                                        const float* __restrict__ Wk,
                                                        const float* __restrict__ Wv,
                                                        float* __restrict__ ksumg,
                                                        float* __restrict__ vsumg) {
    int h = blockIdx.x, cs = blockIdx.y;
    int t = threadIdx.x, lane = t & 63, w = t >> 6;
    int c0 = cs * 64;
    __shared__ float xs[8][64];
    #pragma unroll
    for (int i = 0; i < 2; ++i) {
        int idx = t + i * 256;
        xs[idx >> 6][idx & 63] = xsum[(idx >> 6) * ND + c0 + (idx & 63)];
    }
    __syncthreads();
    float sk[8] = {}, sv[8] = {};
    #pragma unroll 4
    for (int j = 0; j < 16; ++j) {
        int c = c0 + w * 16 + j;
        float wk = Wk[((size_t)h * ND + c) * NDH + lane];
        float wv = Wv[((size_t)h * ND + c) * NDH + lane];
        #pragma unroll
        for (int b = 0; b < 8; ++b) {
            float xv = xs[b][w * 16 + j];
            sk[b] += xv * wk;
            sv[b] += xv * wv;
        }
    }
    __shared__ float red[2][8][4][64];
    #pragma unroll
    for (int b = 0; b < 8; ++b) {
        red[0][b][w][lane] = sk[b];
        red[1][b][w][lane] = sv[b];
    }
    __syncthreads();
    #pragma unroll
    for (int i = 0; i < 4; ++i) {
        int o = t + i * 256;            // 0..1023
        int d = o & 63, rest = o >> 6;  // 0..15
        int a = rest >> 3, b = rest & 7;
        float s = red[a][b][0][d] + red[a][b][1][d] + red[a][b][2][d] + red[a][b][3][d];
        float* dst = a ? vsumg : ksumg;
        atomicAdd(&dst[((size_t)b * NH + h) * NDH + d], s);
    }
}

// ---- wqk[b,h,c] = (Wq[h,c,:] . ksum[b,h,:]) / 8 ----
// grid (16 h, 8 b, 2 csplit); per-thread independent float4 dot (32 loads ILP).
__global__ __launch_bounds__(256) void wqk_kernel(const float* __restrict__ ksumg,
                                                  const float* __restrict__ Wq,
                                                  float* __restrict__ wqk) {
    int h = blockIdx.x, b = blockIdx.y, cs = blockIdx.z;
    int t = threadIdx.x;
    __shared__ float ks[NDH];
    if (t < 64) ks[t] = ksumg[((size_t)b * NH + h) * NDH + t];
    __syncthreads();
    #pragma unroll
    for (int i = 0; i < 2; ++i) {
        int c = cs * 512 + i * 256 + t;
        const float4* wq = (const float4*)(Wq + ((size_t)h * ND + c) * NDH);
        float s = 0.f;
        #pragma unroll
        for (int dq = 0; dq < 16; ++dq) {
            float4 v = wq[dq];
            s += v.x * ks[dq * 4] + v.y * ks[dq * 4 + 1] +
                 v.z * ks[dq * 4 + 2] + v.w * ks[dq * 4 + 3];
        }
        wqk[((size_t)b * NH + h) * ND + c] = s * 0.125f;
    }
}

// ---------------- rowsum[b,h,t] = x[b,t,:] . wqk[b,h,:] ----------------
__global__ __launch_bounds__(256) void rowsum_kernel(const float* __restrict__ x,
                                                     const float* __restrict__ wqk,
                                                     float* __restrict__ rowsum) {
    int tc = blockIdx.x, b = blockIdx.y;
    int tid = threadIdx.x, wid = tid >> 6, lane = tid & 63;
    int t0 = tc * 16 + wid * 4;
    float acc[4][16];
    #pragma unroll
    for (int tq = 0; tq < 4; ++tq)
        #pragma unroll
        for (int h = 0; h < 16; ++h) acc[tq][h] = 0.f;
    const float4* wb = (const float4*)(wqk + (size_t)b * NH * ND);
    #pragma unroll
    for (int chunk = 0; chunk < 4; ++chunk) {
        float4 xv[4];
        #pragma unroll
        for (int tq = 0; tq < 4; ++tq)
            xv[tq] = ((const float4*)(x + ((size_t)b * NT + t0 + tq) * ND))[chunk * 64 + lane];
        #pragma unroll
        for (int h = 0; h < 16; ++h) {
            float4 wv = wb[h * 256 + chunk * 64 + lane];
            #pragma unroll
            for (int tq = 0; tq < 4; ++tq)
                acc[tq][h] += xv[tq].x * wv.x + xv[tq].y * wv.y +
                              xv[tq].z * wv.z + xv[tq].w * wv.w;
        }
    }
    bool c0 = lane & 1, c1 = lane & 2, c2 = lane & 4, c3 = lane & 8;
    float out4[4];
    #pragma unroll
    for (int tq = 0; tq < 4; ++tq) {
        float w8[8];
        #pragma unroll
        for (int j = 0; j < 8; ++j) {
            float send = c0 ? acc[tq][2 * j] : acc[tq][2 * j + 1];
            float recv = __shfl_xor(send, 1, 64);
            w8[j] = (c0 ? acc[tq][2 * j + 1] : acc[tq][2 * j]) + recv;
        }
        float u4[4];
        #pragma unroll
        for (int j = 0; j < 4; ++j) {
            float send = c1 ? w8[2 * j] : w8[2 * j + 1];
            float recv = __shfl_xor(send, 2, 64);
            u4[j] = (c1 ? w8[2 * j + 1] : w8[2 * j]) + recv;
        }
        float s2[2];
        #pragma unroll
        for (int j = 0; j < 2; ++j) {
            float send = c2 ? u4[2 * j] : u4[2 * j + 1];
            float recv = __shfl_xor(send, 4, 64);
            s2[j] = (c2 ? u4[2 * j + 1] : u4[2 * j]) + recv;
        }
        float send = c3 ? s2[0] : s2[1];
        float recv = __shfl_xor(send, 8, 64);
        float r = (c3 ? s2[1] : s2[0]) + recv;
        r += __shfl_xor(r, 16, 64);
        r += __shfl_xor(r, 32, 64);
        out4[tq] = r;
    }
    if (lane < 16) {
        float4 o = {out4[0], out4[1], out4[2], out4[3]};
        *(float4*)(rowsum + ((size_t)b * NH + lane) * NT + t0) = o;
    }
}

// ---------------- softmax over t, in place ----------------
__global__ void softmax_kernel(float* __restrict__ rs) {
    int bh = blockIdx.x, tid = threadIdx.x;
    int wave = tid >> 6, lane = tid & 63;
    float* row = rs + (size_t)bh * NT;
    float4 v = ((float4*)row)[tid];
    float m = fmaxf(fmaxf(v.x, v.y), fmaxf(v.z, v.w));
    __shared__ float red[4];
    for (int off = 32; off; off >>= 1) m = fmaxf(m, __shfl_down(m, off, 64));
    if (lane == 0) red[wave] = m;
    __syncthreads();
    m = fmaxf(fmaxf(red[0], red[1]), fmaxf(red[2], red[3]));
    __syncthreads();
    float4 e;
    e.x = __expf(v.x - m); e.y = __expf(v.y - m);
    e.z = __expf(v.z - m); e.w = __expf(v.w - m);
    float s = e.x + e.y + e.z + e.w;
    for (int off = 32; off; off >>= 1) s += __shfl_down(s, off, 64);
    if (lane == 0) red[wave] = s;
    __syncthreads();
    s = red[0] + red[1] + red[2] + red[3];
    float inv = 1.f / s;
    e.x *= inv; e.y *= inv; e.z *= inv; e.w *= inv;
    ((float4*)row)[tid] = e;
}

// ---------------- LN1: x1 = LN(x + attn_out) -> bf16 ----------------
__global__ void ln1_kernel(const float* __restrict__ x, const float* __restrict__ p,
                           const float* __restrict__ vsum,
                           const float* __restrict__ g1, const float* __restrict__ b1,
                           __bf16* __restrict__ x1b) {
    int t = blockIdx.x, b = blockIdx.y, tid = threadIdx.x;
    int wave = tid >> 6, lane = tid & 63;
    size_t rowoff = ((size_t)b * NT + t) * ND;
    float4 xv = ((const float4*)(x + rowoff))[tid];
    int h = tid >> 4;  // c = tid*4 -> head = c/64
    float pv = p[((size_t)b * NH + h) * NT + t];
    float4 vs = ((const float4*)(vsum + ((size_t)b * NH + h) * NDH))[tid & 15];
    float4 s;
    s.x = xv.x + pv * vs.x; s.y = xv.y + pv * vs.y;
    s.z = xv.z + pv * vs.z; s.w = xv.w + pv * vs.w;
    float sum = s.x + s.y + s.z + s.w;
    float sq = s.x * s.x + s.y * s.y + s.z * s.z + s.w * s.w;
    __shared__ float rs_[4], rq_[4];
    for (int off = 32; off; off >>= 1) {
        sum += __shfl_down(sum, off, 64);
        sq += __shfl_down(sq, off, 64);
    }
    if (lane == 0) { rs_[wave] = sum; rq_[wave] = sq; }
    __syncthreads();
    sum = rs_[0] + rs_[1] + rs_[2] + rs_[3];
    sq = rq_[0] + rq_[1] + rq_[2] + rq_[3];
    float mu = sum * (1.f / ND);
    float var = sq * (1.f / ND) - mu * mu;
    float rstd = rsqrtf(var + LNEPS);
    float4 g = ((const float4*)g1)[tid];
    float4 bb = ((const float4*)b1)[tid];
    union { __bf16 h4[4]; uint2 u; } pk;
    pk.h4[0] = (__bf16)((s.x - mu) * rstd * g.x + bb.x);
    pk.h4[1] = (__bf16)((s.y - mu) * rstd * g.y + bb.y);
    pk.h4[2] = (__bf16)((s.z - mu) * rstd * g.z + bb.z);
    pk.h4[3] = (__bf16)((s.w - mu) * rstd * g.w + bb.w);
    ((uint2*)(x1b + rowoff))[tid] = pk.u;
}

// ---------------- bf16 MFMA GEMM: BK=64, XOR-swizzled LDS, XCD swizzle ----------------
template <int RELU>
__global__ __launch_bounds__(256) void gemm_bf16(const __bf16* __restrict__ A,
                                                 const __bf16* __restrict__ BT,
                                                 __bf16* __restrict__ Cout) {
    const int K = 1024, N = 1024;
    __shared__ __bf16 As[128 * 64];
    __shared__ __bf16 Bs[128 * 64];
    int raw = blockIdx.x;
    int swz = (raw & 7) * 64 + (raw >> 3);   // XCD k owns swz in [k*64, k*64+64)
    int m0 = (swz >> 3) * 128;               // 8 m-panels per XCD
    int n0 = (swz & 7) * 128;                // all 8 n-panels (B L2-resident)
    int tid = threadIdx.x;
    int wid = tid >> 6, lane = tid & 63;
    int wr = wid >> 1, wc = wid & 1;
    int r = lane & 15, g = lane >> 4;
    int srow = tid >> 3;                                      // 0..31
    int soff_e = (((tid & 7) * 16) ^ ((srow & 7) << 4)) >> 1; // elements
    const __bf16* Ag = A + (size_t)(m0 + srow) * K + soff_e;
    const __bf16* Bg = BT + (size_t)(n0 + srow) * K + soff_e;
    int swz_r = (r & 7) << 4;
    f32x4 acc[4][4] = {};
    for (int k0 = 0; k0 < K; k0 += 64) {
        __syncthreads();
        #pragma unroll
        for (int j = 0; j < 4; ++j) {
            __builtin_amdgcn_global_load_lds(
                (const __attribute__((address_space(1))) unsigned int*)(Ag + (size_t)(j * 32) * K + k0),
                (__attribute__((address_space(3))) unsigned int*)&As[(j * 32 + wid * 8) * 64], 16, 0, 0);
            __builtin_amdgcn_global_load_lds(
                (const __attribute__((address_space(1))) unsigned int*)(Bg + (size_t)(j * 32) * K + k0),
                (__attribute__((address_space(3))) unsigned int*)&Bs[(j * 32 + wid * 8) * 64], 16, 0, 0);
        }
        __syncthreads();
        #pragma unroll
        for (int ks = 0; ks < 2; ++ks) {
            int ob = (ks * 64 + g * 16) ^ swz_r;  // byte within 128-B row
            bf16x8 af[4], bf[4];
            #pragma unroll
            for (int mf = 0; mf < 4; ++mf)
                af[mf] = *(const bf16x8*)((const char*)&As[(wr * 64 + mf * 16 + r) * 64] + ob);
            #pragma unroll
            for (int nf = 0; nf < 4; ++nf)
                bf[nf] = *(const bf16x8*)((const char*)&Bs[(wc * 64 + nf * 16 + r) * 64] + ob);
            #pragma unroll
            for (int mf = 0; mf < 4; ++mf)
                #pragma unroll
                for (int nf = 0; nf < 4; ++nf)
                    acc[mf][nf] = __builtin_amdgcn_mfma_f32_16x16x32_bf16(af[mf], bf[nf], acc[mf][nf], 0, 0, 0);
        }
    }
    #pragma unroll
    for (int mf = 0; mf < 4; ++mf) {
        #pragma unroll
        for (int nf = 0; nf < 4; ++nf) {
            int col = n0 + wc * 64 + nf * 16 + r;
            #pragma unroll
            for (int i = 0; i < 4; ++i) {
                int row = m0 + wr * 64 + mf * 16 + g * 4 + i;
                float v = acc[mf][nf][i];
                if (RELU) v = fmaxf(v, 0.f);
                Cout[(size_t)row * N + col] = (__bf16)v;
            }
        }
    }
}

// ---------------- LN2: out = LN(x1 + ff) -> f32 ----------------
__global__ void ln2_kernel(const __bf16* __restrict__ x1b, const __bf16* __restrict__ ffb,
                           float* __restrict__ out,
                           const float* __restrict__ g2, const float* __restrict__ b2) {
    int t = blockIdx.x, b = blockIdx.y, tid = threadIdx.x;
    int wave = tid >> 6, lane = tid & 63;
    size_t rowoff = ((size_t)b * NT + t) * ND;
    union { __bf16 h4[4]; uint2 u; } pk, pf;
    pk.u = ((const uint2*)(x1b + rowoff))[tid];
    pf.u = ((const uint2*)(ffb + rowoff))[tid];
    float4 s;
    s.x = (float)pk.h4[0] + (float)pf.h4[0];
    s.y = (float)pk.h4[1] + (float)pf.h4[1];
    s.z = (float)pk.h4[2] + (float)pf.h4[2];
    s.w = (float)pk.h4[3] + (float)pf.h4[3];
    float sum = s.x + s.y + s.z + s.w;
    float sq = s.x * s.x + s.y * s.y + s.z * s.z + s.w * s.w;
    __shared__ float rs_[4], rq_[4];
    for (int off = 32; off; off >>= 1) {
        sum += __shfl_down(sum, off, 64);
        sq += __shfl_down(sq, off, 64);
    }
    if (lane == 0) { rs_[wave] = sum; rq_[wave] = sq; }
    __syncthreads();
    sum = rs_[0] + rs_[1] + rs_[2] + rs_[3];
    sq = rq_[0] + rq_[1] + rq_[2] + rq_[3];
    float mu = sum * (1.f / ND);
    float var = sq * (1.f / ND) - mu * mu;
    float rstd = rsqrtf(var + LNEPS);
    float4 g = ((const float4*)g2)[tid];
    float4 bb = ((const float4*)b2)[tid];
    float4 o;
    o.x = (s.x - mu) * rstd * g.x + bb.x;
    o.y = (s.y - mu) * rstd * g.y + bb.y;
    o.z = (s.z - mu) * rstd * g.z + bb.z;
    o.w = (s.w - mu) * rstd * g.w + bb.w;
    ((float4*)(out + rowoff))[tid] = o;
}

extern "C" void kernel_launch(void* const* d_in, const int* in_sizes, int n_in,
                              void* d_out, int out_size, void* d_ws, size_t ws_size,
                              hipStream_t stream) {
    const float* x  = (const float*)d_in[0];
    const float* Wq = (const float*)d_in[1];
    const float* Wk = (const float*)d_in[2];
    const float* Wv = (const float*)d_in[3];
    const float* W1 = (const float*)d_in[4];
    const float* W2 = (const float*)d_in[5];
    const float* g1 = (const float*)d_in[6];
    const float* b1 = (const float*)d_in[7];
    const float* g2 = (const float*)d_in[8];
    const float* b2 = (const float*)d_in[9];
    float* out = (float*)d_out;

    char* w = (char*)d_ws;
    float* xsum  = (float*)w;  w += (size_t)NB * ND * 4;            // 32 KB  (zeroed)
    float* ksumg = (float*)w;  w += (size_t)NB * NH * NDH * 4;      // 32 KB  (zeroed)
    float* vsum  = (float*)w;  w += (size_t)NB * NH * NDH * 4;      // 32 KB  (zeroed)
    float* wqk   = (float*)w;  w += (size_t)NB * NH * ND * 4;       // 512 KB
    float* rsum  = (float*)w;  w += (size_t)NB * NH * NT * 4;       // 512 KB
    __bf16* x1b = (__bf16*)w;  w += (size_t)NM * ND * 2;            // 16 MB
    __bf16* h1b = (__bf16*)w;  w += (size_t)NM * ND * 2;            // 16 MB
    __bf16* ffb = (__bf16*)w;  w += (size_t)NM * ND * 2;            // 16 MB
    __bf16* w1t = (__bf16*)w;  w += (size_t)ND * ND * 2;            // 2 MB
    __bf16* w2t = (__bf16*)w;  w += (size_t)ND * ND * 2;            // 2 MB

    // zero xsum + ksum + vsum accumulators (contiguous, 96 KB)
    hipMemsetAsync(xsum, 0, (size_t)(NB * ND + 2 * NB * NH * NDH) * 4, stream);

    // weight transpose+convert (f32 KxN -> bf16 NxK), W1 and W2 in one dispatch
    transpose_to_bf16<<<dim3(32, 32, 2), dim3(32, 8), 0, stream>>>(W1, W2, w1t, w2t);

    // attention (algebraically reduced)
    xsum_kernel<<<dim3(NB, 64), 256, 0, stream>>>(x, xsum);
    ksum_vsum_kernel<<<dim3(NH, 16), 256, 0, stream>>>(xsum, Wk, Wv, ksumg, vsum);
    wqk_kernel<<<dim3(NH, NB, 2), 256, 0, stream>>>(ksumg, Wq, wqk);
    rowsum_kernel<<<dim3(64, NB), 256, 0, stream>>>(x, wqk, rsum);
    softmax_kernel<<<NB * NH, 256, 0, stream>>>(rsum);
    ln1_kernel<<<dim3(NT, NB), 256, 0, stream>>>(x, rsum, vsum, g1, b1, x1b);

    // FFN
    gemm_bf16<1><<<512, 256, 0, stream>>>(x1b, w1t, h1b);
    gemm_bf16<0><<<512, 256, 0, stream>>>(h1b, w2t, ffb);
    ln2_kernel<<<dim3(NT, NB), 256, 0, stream>>>(x1b, ffb, out, g2, b2);
}

// Round 8
// 219.864 us; speedup vs baseline: 1.0944x; 1.0181x over previous
//
#include <hip/hip_runtime.h>

#define NB 8
#define NT 1024
#define ND 1024
#define NH 16
#define NDH 64
#define NM (NB*NT)   // 8192 rows
#define LNEPS 1e-5f

typedef __attribute__((ext_vector_type(8))) __bf16 bf16x8;
typedef __attribute__((ext_vector_type(4))) float f32x4;

// ---------------- W (K x N f32) -> WT (N x K bf16), both W1 and W2 ----------------
__global__ void transpose_to_bf16(const float* __restrict__ W1, const float* __restrict__ W2,
                                  __bf16* __restrict__ WT1, __bf16* __restrict__ WT2) {
    __shared__ float tile[32][33];
    const float* W = blockIdx.z ? W2 : W1;
    __bf16* WT = blockIdx.z ? WT2 : WT1;
    int bx = blockIdx.x * 32;  // n base
    int by = blockIdx.y * 32;  // k base
    int tx = threadIdx.x;      // 0..31
    int ty = threadIdx.y;      // 0..7
    for (int i = ty; i < 32; i += 8)
        tile[i][tx] = W[(size_t)(by + i) * ND + bx + tx];
    __syncthreads();
    for (int i = ty; i < 32; i += 8)
        WT[(size_t)(bx + i) * ND + by + tx] = (__bf16)tile[tx][i];
}

// ---------------- xsum[b,c] += partial sums over t ----------------
__global__ void xsum_kernel(const float* __restrict__ x, float* __restrict__ xsum) {
    int b = blockIdx.x;
    int chunk = blockIdx.y;
    int tid = threadIdx.x;
    const float4* xp = (const float4*)(x + ((size_t)b * NT + chunk * 16) * ND) + tid;
    float4 s = {0.f, 0.f, 0.f, 0.f};
    #pragma unroll
    for (int t = 0; t < 16; ++t) {
        float4 v = xp[(size_t)t * (ND / 4)];
        s.x += v.x; s.y += v.y; s.z += v.z; s.w += v.w;
    }
    float* dst = xsum + b * ND + tid * 4;
    atomicAdd(dst + 0, s.x);
    atomicAdd(dst + 1, s.y);
    atomicAdd(dst + 2, s.z);
    atomicAdd(dst + 3, s.w);
}

// ---- ksum[b,h,d], vsum[b,h,d] = sum_c xsum[b,c] * Wk/Wv[h,c,d] ----
__global__ __launch_bounds__(256) void ksum_vsum_kernel(const float* __restrict__ xsum,
                                                        const float* __restrict__ Wk,
                                                        const float* __restrict__ Wv,
                                                        float* __restrict__ ksumg,
                                                        float* __restrict__ vsumg) {
    int h = blockIdx.x, cs = blockIdx.y;
    int t = threadIdx.x, lane = t & 63, w = t >> 6;
    int c0 = cs * 64;
    __shared__ float xs[8][64];
    #pragma unroll
    for (int i = 0; i < 2; ++i) {
        int idx = t + i * 256;
        xs[idx >> 6][idx & 63] = xsum[(idx >> 6) * ND + c0 + (idx & 63)];
    }
    __syncthreads();
    float sk[8] = {}, sv[8] = {};
    #pragma unroll 4
    for (int j = 0; j < 16; ++j) {
        int c = c0 + w * 16 + j;
        float wk = Wk[((size_t)h * ND + c) * NDH + lane];
        float wv = Wv[((size_t)h * ND + c) * NDH + lane];
        #pragma unroll
        for (int b = 0; b < 8; ++b) {
            float xv = xs[b][w * 16 + j];
            sk[b] += xv * wk;
            sv[b] += xv * wv;
        }
    }
    __shared__ float red[2][8][4][64];
    #pragma unroll
    for (int b = 0; b < 8; ++b) {
        red[0][b][w][lane] = sk[b];
        red[1][b][w][lane] = sv[b];
    }
    __syncthreads();
    #pragma unroll
    for (int i = 0; i < 4; ++i) {
        int o = t + i * 256;            // 0..1023
        int d = o & 63, rest = o >> 6;  // 0..15
        int a = rest >> 3, b = rest & 7;
        float s = red[a][b][0][d] + red[a][b][1][d] + red[a][b][2][d] + red[a][b][3][d];
        float* dst = a ? vsumg : ksumg;
        atomicAdd(&dst[((size_t)b * NH + h) * NDH + d], s);
    }
}

// ---- wqk[b,h,c] = (Wq[h,c,:] . ksum[b,h,:]) / 8 ----
__global__ __launch_bounds__(256) void wqk_kernel(const float* __restrict__ ksumg,
                                                  const float* __restrict__ Wq,
                                                  float* __restrict__ wqk) {
    int h = blockIdx.x, b = blockIdx.y, cs = blockIdx.z;
    int t = threadIdx.x;
    __shared__ float ks[NDH];
    if (t < 64) ks[t] = ksumg[((size_t)b * NH + h) * NDH + t];
    __syncthreads();
    #pragma unroll
    for (int i = 0; i < 2; ++i) {
        int c = cs * 512 + i * 256 + t;
        const float4* wq = (const float4*)(Wq + ((size_t)h * ND + c) * NDH);
        float s = 0.f;
        #pragma unroll
        for (int dq = 0; dq < 16; ++dq) {
            float4 v = wq[dq];
            s += v.x * ks[dq * 4] + v.y * ks[dq * 4 + 1] +
                 v.z * ks[dq * 4 + 2] + v.w * ks[dq * 4 + 3];
        }
        wqk[((size_t)b * NH + h) * ND + c] = s * 0.125f;
    }
}

// ---------------- rowsum[b,h,t] = x[b,t,:] . wqk[b,h,:] ----------------
__global__ __launch_bounds__(256) void rowsum_kernel(const float* __restrict__ x,
                                                     const float* __restrict__ wqk,
                                                     float* __restrict__ rowsum) {
    int tc = blockIdx.x, b = blockIdx.y;
    int tid = threadIdx.x, wid = tid >> 6, lane = tid & 63;
    int t0 = tc * 16 + wid * 4;
    float acc[4][16];
    #pragma unroll
    for (int tq = 0; tq < 4; ++tq)
        #pragma unroll
        for (int h = 0; h < 16; ++h) acc[tq][h] = 0.f;
    const float4* wb = (const float4*)(wqk + (size_t)b * NH * ND);
    #pragma unroll
    for (int chunk = 0; chunk < 4; ++chunk) {
        float4 xv[4];
        #pragma unroll
        for (int tq = 0; tq < 4; ++tq)
            xv[tq] = ((const float4*)(x + ((size_t)b * NT + t0 + tq) * ND))[chunk * 64 + lane];
        #pragma unroll
        for (int h = 0; h < 16; ++h) {
            float4 wv = wb[h * 256 + chunk * 64 + lane];
            #pragma unroll
            for (int tq = 0; tq < 4; ++tq)
                acc[tq][h] += xv[tq].x * wv.x + xv[tq].y * wv.y +
                              xv[tq].z * wv.z + xv[tq].w * wv.w;
        }
    }
    bool c0 = lane & 1, c1 = lane & 2, c2 = lane & 4, c3 = lane & 8;
    float out4[4];
    #pragma unroll
    for (int tq = 0; tq < 4; ++tq) {
        float w8[8];
        #pragma unroll
        for (int j = 0; j < 8; ++j) {
            float send = c0 ? acc[tq][2 * j] : acc[tq][2 * j + 1];
            float recv = __shfl_xor(send, 1, 64);
            w8[j] = (c0 ? acc[tq][2 * j + 1] : acc[tq][2 * j]) + recv;
        }
        float u4[4];
        #pragma unroll
        for (int j = 0; j < 4; ++j) {
            float send = c1 ? w8[2 * j] : w8[2 * j + 1];
            float recv = __shfl_xor(send, 2, 64);
            u4[j] = (c1 ? w8[2 * j + 1] : w8[2 * j]) + recv;
        }
        float s2[2];
        #pragma unroll
        for (int j = 0; j < 2; ++j) {
            float send = c2 ? u4[2 * j] : u4[2 * j + 1];
            float recv = __shfl_xor(send, 4, 64);
            s2[j] = (c2 ? u4[2 * j + 1] : u4[2 * j]) + recv;
        }
        float send = c3 ? s2[0] : s2[1];
        float recv = __shfl_xor(send, 8, 64);
        float r = (c3 ? s2[1] : s2[0]) + recv;
        r += __shfl_xor(r, 16, 64);
        r += __shfl_xor(r, 32, 64);
        out4[tq] = r;
    }
    if (lane < 16) {
        float4 o = {out4[0], out4[1], out4[2], out4[3]};
        *(float4*)(rowsum + ((size_t)b * NH + lane) * NT + t0) = o;
    }
}

// ---------------- softmax over t, in place ----------------
__global__ void softmax_kernel(float* __restrict__ rs) {
    int bh = blockIdx.x, tid = threadIdx.x;
    int wave = tid >> 6, lane = tid & 63;
    float* row = rs + (size_t)bh * NT;
    float4 v = ((float4*)row)[tid];
    float m = fmaxf(fmaxf(v.x, v.y), fmaxf(v.z, v.w));
    __shared__ float red[4];
    for (int off = 32; off; off >>= 1) m = fmaxf(m, __shfl_down(m, off, 64));
    if (lane == 0) red[wave] = m;
    __syncthreads();
    m = fmaxf(fmaxf(red[0], red[1]), fmaxf(red[2], red[3]));
    __syncthreads();
    float4 e;
    e.x = __expf(v.x - m); e.y = __expf(v.y - m);
    e.z = __expf(v.z - m); e.w = __expf(v.w - m);
    float s = e.x + e.y + e.z + e.w;
    for (int off = 32; off; off >>= 1) s += __shfl_down(s, off, 64);
    if (lane == 0) red[wave] = s;
    __syncthreads();
    s = red[0] + red[1] + red[2] + red[3];
    float inv = 1.f / s;
    e.x *= inv; e.y *= inv; e.z *= inv; e.w *= inv;
    ((float4*)row)[tid] = e;
}

// ---------------- LN1: x1 = LN(x + attn_out) -> bf16 ----------------
__global__ void ln1_kernel(const float* __restrict__ x, const float* __restrict__ p,
                           const float* __restrict__ vsum,
                           const float* __restrict__ g1, const float* __restrict__ b1,
                           __bf16* __restrict__ x1b) {
    int t = blockIdx.x, b = blockIdx.y, tid = threadIdx.x;
    int wave = tid >> 6, lane = tid & 63;
    size_t rowoff = ((size_t)b * NT + t) * ND;
    float4 xv = ((const float4*)(x + rowoff))[tid];
    int h = tid >> 4;  // c = tid*4 -> head = c/64
    float pv = p[((size_t)b * NH + h) * NT + t];
    float4 vs = ((const float4*)(vsum + ((size_t)b * NH + h) * NDH))[tid & 15];
    float4 s;
    s.x = xv.x + pv * vs.x; s.y = xv.y + pv * vs.y;
    s.z = xv.z + pv * vs.z; s.w = xv.w + pv * vs.w;
    float sum = s.x + s.y + s.z + s.w;
    float sq = s.x * s.x + s.y * s.y + s.z * s.z + s.w * s.w;
    __shared__ float rs_[4], rq_[4];
    for (int off = 32; off; off >>= 1) {
        sum += __shfl_down(sum, off, 64);
        sq += __shfl_down(sq, off, 64);
    }
    if (lane == 0) { rs_[wave] = sum; rq_[wave] = sq; }
    __syncthreads();
    sum = rs_[0] + rs_[1] + rs_[2] + rs_[3];
    sq = rq_[0] + rq_[1] + rq_[2] + rq_[3];
    float mu = sum * (1.f / ND);
    float var = sq * (1.f / ND) - mu * mu;
    float rstd = rsqrtf(var + LNEPS);
    float4 g = ((const float4*)g1)[tid];
    float4 bb = ((const float4*)b1)[tid];
    union { __bf16 h4[4]; uint2 u; } pk;
    pk.h4[0] = (__bf16)((s.x - mu) * rstd * g.x + bb.x);
    pk.h4[1] = (__bf16)((s.y - mu) * rstd * g.y + bb.y);
    pk.h4[2] = (__bf16)((s.z - mu) * rstd * g.z + bb.z);
    pk.h4[3] = (__bf16)((s.w - mu) * rstd * g.w + bb.w);
    ((uint2*)(x1b + rowoff))[tid] = pk.u;
}

// ------- bf16 MFMA GEMM, pipelined: BM=128 BN=256 BK=64, 512 thr / 8 waves -------
// 3-deep LDS rotation (144 KB), counted s_waitcnt vmcnt(6) (never 0 in main loop),
// ONE raw s_barrier per K-step, setprio around MFMA, XOR LDS swizzle (both sides),
// XCD-bijective block swizzle (256 blocks, 256%8==0).
template <int RELU>
__global__ __launch_bounds__(512, 1) void gemm_bf16(const __bf16* __restrict__ A,
                                                    const __bf16* __restrict__ BT,
                                                    __bf16* __restrict__ Cout) {
    const int K = 1024, N = 1024;
    const int NTILES = K / 64;                 // 16
    const int BUFE = (128 + 256) * 64;         // elements per buffer (A then B)
    __shared__ __bf16 lds[3 * BUFE];           // 144 KB
    int raw = blockIdx.x;
    int swz = (raw & 7) * 32 + (raw >> 3);     // XCD k owns swz in [k*32, k*32+32)
    int m0 = (swz >> 2) * 128;                 // 64 m-tiles
    int n0 = (swz & 3) * 256;                  // 4 n-tiles (B panel L2-resident per XCD)
    int tid = threadIdx.x;
    int wid = tid >> 6, lane = tid & 63;
    int wr = wid >> 2, wc = wid & 3;           // wave grid 2M x 4N -> 64x64 per wave
    int r = lane & 15, g = lane >> 4;
    // staging: issue j covers 64 rows; thread -> row (tid>>3), 16B col (tid&7)*16,
    // global col pre-XOR'd by ((row&7)<<4); LDS dest linear (wave-uniform base).
    int srow = tid >> 3;                                      // 0..63
    int soff_e = (((tid & 7) * 16) ^ ((srow & 7) << 4)) >> 1; // elements 0..63
    const __bf16* Ag = A + (size_t)(m0 + srow) * K + soff_e;
    const __bf16* Bg = BT + (size_t)(n0 + srow) * K + soff_e;
    int ldst = wid * 512;                                     // wave-uniform, +lane*16B by HW
    int swz_r = (r & 7) << 4;
    f32x4 acc[4][4] = {};

    #define GL(gp, le)                                                              \
        __builtin_amdgcn_global_load_lds(                                           \
            (const __attribute__((address_space(1))) unsigned int*)(gp),            \
            (__attribute__((address_space(3))) unsigned int*)&lds[le], 16, 0, 0)
    #define STAGE(tile, buf) do {                                                   \
        const __bf16* ag_ = Ag + (size_t)(tile) * 64;                               \
        const __bf16* bg_ = Bg + (size_t)(tile) * 64;                               \
        int ab_ = (buf) * BUFE, bb_ = ab_ + 128 * 64;                               \
        GL(ag_,                 ab_ + ldst);                                        \
        GL(ag_ + (size_t)64*K,  ab_ + 4096 + ldst);                                 \
        GL(bg_,                 bb_ + ldst);                                        \
        GL(bg_ + (size_t)64*K,  bb_ + 4096 + ldst);                                 \
        GL(bg_ + (size_t)128*K, bb_ + 8192 + ldst);                                 \
        GL(bg_ + (size_t)192*K, bb_ + 12288 + ldst);                                \
    } while (0)

    STAGE(0, 0);
    STAGE(1, 1);
    int cur = 0;
    for (int t = 0; t < NTILES; ++t) {
        if (t < NTILES - 1) {
            asm volatile("s_waitcnt vmcnt(6)" ::: "memory");
        } else {
            asm volatile("s_waitcnt vmcnt(0)" ::: "memory");
        }
        __builtin_amdgcn_s_barrier();
        // all waves: tile t landed, and everyone finished compute(t-1) ->
        // safe to overwrite buf[(t+2)%3] (last read at compute(t-1)).
        if (t + 2 < NTILES) {
            int nb = cur + 2; if (nb >= 3) nb -= 3;
            STAGE(t + 2, nb);
        }
        const __bf16* la = &lds[cur * BUFE];
        const __bf16* lb = la + 128 * 64;
        #pragma unroll
        for (int ks = 0; ks < 2; ++ks) {
            int ob = (ks * 64 + g * 16) ^ swz_r;  // byte within 128-B row
            bf16x8 af[4], bf[4];
            #pragma unroll
            for (int mf = 0; mf < 4; ++mf)
                af[mf] = *(const bf16x8*)((const char*)&la[(wr * 64 + mf * 16 + r) * 64] + ob);
            #pragma unroll
            for (int nf = 0; nf < 4; ++nf)
                bf[nf] = *(const bf16x8*)((const char*)&lb[(wc * 64 + nf * 16 + r) * 64] + ob);
            __builtin_amdgcn_s_setprio(1);
            #pragma unroll
            for (int mf = 0; mf < 4; ++mf)
                #pragma unroll
                for (int nf = 0; nf < 4; ++nf)
                    acc[mf][nf] = __builtin_amdgcn_mfma_f32_16x16x32_bf16(af[mf], bf[nf], acc[mf][nf], 0, 0, 0);
            __builtin_amdgcn_s_setprio(0);
        }
        ++cur; if (cur >= 3) cur = 0;
    }
    #undef STAGE
    #undef GL

    #pragma unroll
    for (int mf = 0; mf < 4; ++mf) {
        #pragma unroll
        for (int nf = 0; nf < 4; ++nf) {
            int col = n0 + wc * 64 + nf * 16 + r;
            #pragma unroll
            for (int i = 0; i < 4; ++i) {
                int row = m0 + wr * 64 + mf * 16 + g * 4 + i;
                float v = acc[mf][nf][i];
                if (RELU) v = fmaxf(v, 0.f);
                Cout[(size_t)row * N + col] = (__bf16)v;
            }
        }
    }
}

// ---------------- LN2: out = LN(x1 + ff) -> f32 ----------------
__global__ void ln2_kernel(const __bf16* __restrict__ x1b, const __bf16* __restrict__ ffb,
                           float* __restrict__ out,
                           const float* __restrict__ g2, const float* __restrict__ b2) {
    int t = blockIdx.x, b = blockIdx.y, tid = threadIdx.x;
    int wave = tid >> 6, lane = tid & 63;
    size_t rowoff = ((size_t)b * NT + t) * ND;
    union { __bf16 h4[4]; uint2 u; } pk, pf;
    pk.u = ((const uint2*)(x1b + rowoff))[tid];
    pf.u = ((const uint2*)(ffb + rowoff))[tid];
    float4 s;
    s.x = (float)pk.h4[0] + (float)pf.h4[0];
    s.y = (float)pk.h4[1] + (float)pf.h4[1];
    s.z = (float)pk.h4[2] + (float)pf.h4[2];
    s.w = (float)pk.h4[3] + (float)pf.h4[3];
    float sum = s.x + s.y + s.z + s.w;
    float sq = s.x * s.x + s.y * s.y + s.z * s.z + s.w * s.w;
    __shared__ float rs_[4], rq_[4];
    for (int off = 32; off; off >>= 1) {
        sum += __shfl_down(sum, off, 64);
        sq += __shfl_down(sq, off, 64);
    }
    if (lane == 0) { rs_[wave] = sum; rq_[wave] = sq; }
    __syncthreads();
    sum = rs_[0] + rs_[1] + rs_[2] + rs_[3];
    sq = rq_[0] + rq_[1] + rq_[2] + rq_[3];
    float mu = sum * (1.f / ND);
    float var = sq * (1.f / ND) - mu * mu;
    float rstd = rsqrtf(var + LNEPS);
    float4 g = ((const float4*)g2)[tid];
    float4 bb = ((const float4*)b2)[tid];
    float4 o;
    o.x = (s.x - mu) * rstd * g.x + bb.x;
    o.y = (s.y - mu) * rstd * g.y + bb.y;
    o.z = (s.z - mu) * rstd * g.z + bb.z;
    o.w = (s.w - mu) * rstd * g.w + bb.w;
    ((float4*)(out + rowoff))[tid] = o;
}

extern "C" void kernel_launch(void* const* d_in, const int* in_sizes, int n_in,
                              void* d_out, int out_size, void* d_ws, size_t ws_size,
                              hipStream_t stream) {
    const float* x  = (const float*)d_in[0];
    const float* Wq = (const float*)d_in[1];
    const float* Wk = (const float*)d_in[2];
    const float* Wv = (const float*)d_in[3];
    const float* W1 = (const float*)d_in[4];
    const float* W2 = (const float*)d_in[5];
    const float* g1 = (const float*)d_in[6];
    const float* b1 = (const float*)d_in[7];
    const float* g2 = (const float*)d_in[8];
    const float* b2 = (const float*)d_in[9];
    float* out = (float*)d_out;

    char* w = (char*)d_ws;
    float* xsum  = (float*)w;  w += (size_t)NB * ND * 4;            // 32 KB  (zeroed)
    float* ksumg = (float*)w;  w += (size_t)NB * NH * NDH * 4;      // 32 KB  (zeroed)
    float* vsum  = (float*)w;  w += (size_t)NB * NH * NDH * 4;      // 32 KB  (zeroed)
    float* wqk   = (float*)w;  w += (size_t)NB * NH * ND * 4;       // 512 KB
    float* rsum  = (float*)w;  w += (size_t)NB * NH * NT * 4;       // 512 KB
    __bf16* x1b = (__bf16*)w;  w += (size_t)NM * ND * 2;            // 16 MB
    __bf16* h1b = (__bf16*)w;  w += (size_t)NM * ND * 2;            // 16 MB
    __bf16* ffb = (__bf16*)w;  w += (size_t)NM * ND * 2;            // 16 MB
    __bf16* w1t = (__bf16*)w;  w += (size_t)ND * ND * 2;            // 2 MB
    __bf16* w2t = (__bf16*)w;  w += (size_t)ND * ND * 2;            // 2 MB

    // zero xsum + ksum + vsum accumulators (contiguous, 96 KB)
    hipMemsetAsync(xsum, 0, (size_t)(NB * ND + 2 * NB * NH * NDH) * 4, stream);

    // weight transpose+convert (f32 KxN -> bf16 NxK), W1 and W2 in one dispatch
    transpose_to_bf16<<<dim3(32, 32, 2), dim3(32, 8), 0, stream>>>(W1, W2, w1t, w2t);

    // attention (algebraically reduced)
    xsum_kernel<<<dim3(NB, 64), 256, 0, stream>>>(x, xsum);
    ksum_vsum_kernel<<<dim3(NH, 16), 256, 0, stream>>>(xsum, Wk, Wv, ksumg, vsum);
    wqk_kernel<<<dim3(NH, NB, 2), 256, 0, stream>>>(ksumg, Wq, wqk);
    rowsum_kernel<<<dim3(64, NB), 256, 0, stream>>>(x, wqk, rsum);
    softmax_kernel<<<NB * NH, 256, 0, stream>>>(rsum);
    ln1_kernel<<<dim3(NT, NB), 256, 0, stream>>>(x, rsum, vsum, g1, b1, x1b);

    // FFN (pipelined MFMA GEMMs, 256 blocks x 512 threads)
    gemm_bf16<1><<<256, 512, 0, stream>>>(x1b, w1t, h1b);
    gemm_bf16<0><<<256, 512, 0, stream>>>(h1b, w2t, ffb);
    ln2_kernel<<<dim3(NT, NB), 256, 0, stream>>>(x1b, ffb, out, g2, b2);
}